// Round 1
// baseline (131.261 us; speedup 1.0000x reference)
//
#include <hip/hip_runtime.h>

#define BB 32
#define TT 1024
#define DD 512
#define HH 10

// ws layout: E [BB*TT] floats, then cbh [BB*HH] floats

// ---------------------------------------------------------------------------
// k0: zero context output, copy rnn -> second output half, compute
//     cbh[b][h] = sum_f rnn[b,f] * W1[D+f, h] + b1[h]
// ---------------------------------------------------------------------------
__global__ __launch_bounds__(256) void k0_init(
    const float* __restrict__ rnn, const float* __restrict__ W1,
    const float* __restrict__ b1, float* __restrict__ out,
    float* __restrict__ cbh) {
  const int b = blockIdx.x;
  const int tid = threadIdx.x;  // 256

  const float r0 = rnn[b * DD + tid];
  const float r1 = rnn[b * DD + tid + 256];

  // zero context half, copy rnn to second half
  out[b * DD + tid] = 0.f;
  out[b * DD + tid + 256] = 0.f;
  out[BB * DD + b * DD + tid] = r0;
  out[BB * DD + b * DD + tid + 256] = r1;

  float s[HH];
#pragma unroll
  for (int h = 0; h < HH; ++h) {
    s[h] = r0 * W1[(DD + tid) * HH + h] + r1 * W1[(DD + tid + 256) * HH + h];
  }

  __shared__ float red[256][HH];
#pragma unroll
  for (int h = 0; h < HH; ++h) red[tid][h] = s[h];
  __syncthreads();
  for (int off = 128; off > 0; off >>= 1) {
    if (tid < off) {
#pragma unroll
      for (int h = 0; h < HH; ++h) red[tid][h] += red[tid + off][h];
    }
    __syncthreads();
  }
  if (tid < HH) cbh[b * HH + tid] = red[0][tid] + b1[tid];
}

// ---------------------------------------------------------------------------
// kA: energies.  One wave per row (b,t).  Lane L covers f in
//     {4L..4L+3} u {256+4L..256+4L+3}; W1a kept in registers.
// ---------------------------------------------------------------------------
__global__ __launch_bounds__(256, 4) void kA_energies(
    const float* __restrict__ x, const float* __restrict__ W1,
    const float* __restrict__ cbh, const float* __restrict__ W2,
    const float* __restrict__ b2, float* __restrict__ E) {
  const int lane = threadIdx.x & 63;
  const int wid = blockIdx.x * (blockDim.x >> 6) + (threadIdx.x >> 6);
  const int f0 = lane * 4;

  // per-lane weight fragments (80 VGPRs)
  float wA[4][HH], wB[4][HH];
#pragma unroll
  for (int k = 0; k < 4; ++k) {
#pragma unroll
    for (int h = 0; h < HH; ++h) {
      wA[k][h] = W1[(f0 + k) * HH + h];
      wB[k][h] = W1[(256 + f0 + k) * HH + h];
    }
  }
  // uniform scalars (SGPRs)
  float w2r[HH];
#pragma unroll
  for (int h = 0; h < HH; ++h) w2r[h] = W2[h];
  const float b2v = b2[0];

  const int NW = 4096;  // 1024 blocks * 4 waves
  for (int row = wid; row < BB * TT; row += NW) {
    const float4 x0 = *reinterpret_cast<const float4*>(x + row * DD + f0);
    const float4 x1 = *reinterpret_cast<const float4*>(x + row * DD + 256 + f0);

    float s[HH];
#pragma unroll
    for (int h = 0; h < HH; ++h) {
      float v = x0.x * wA[0][h];
      v = fmaf(x0.y, wA[1][h], v);
      v = fmaf(x0.z, wA[2][h], v);
      v = fmaf(x0.w, wA[3][h], v);
      v = fmaf(x1.x, wB[0][h], v);
      v = fmaf(x1.y, wB[1][h], v);
      v = fmaf(x1.z, wB[2][h], v);
      v = fmaf(x1.w, wB[3][h], v);
      s[h] = v;
    }
    // wave-wide butterfly reduce each of the 10 partials
#pragma unroll
    for (int h = 0; h < HH; ++h) {
      float v = s[h];
#pragma unroll
      for (int off = 32; off > 0; off >>= 1) v += __shfl_xor(v, off, 64);
      s[h] = v;
    }
    const int b = row >> 10;
    float e = b2v;
#pragma unroll
    for (int h = 0; h < HH; ++h) {
      const float v = s[h] + cbh[b * HH + h];
      // tanh(v) = 1 - 2/(exp(2v)+1)
      const float z = __expf(2.f * v);
      const float th = 1.f - 2.f * __builtin_amdgcn_rcpf(z + 1.f);
      e = fmaf(th, w2r[h], e);
    }
    if (lane == 0) E[row] = fmaxf(e, 0.f);
  }
}

// ---------------------------------------------------------------------------
// kB: fused softmax (redundant per t-chunk block, energies are L2-hot) +
//     context accumulation.  Grid = 32 b * 16 t-chunks; block = 256 threads,
//     each thread owns 2 d's (float2).
// ---------------------------------------------------------------------------
__global__ __launch_bounds__(256) void kB_context(
    const float* __restrict__ x, const float* __restrict__ E,
    float* __restrict__ out) {
  const int tid = threadIdx.x;  // 256
  const int b = blockIdx.x >> 4;
  const int tc = blockIdx.x & 15;

  __shared__ float we[TT];
  __shared__ float red[256];

  // each thread loads 4 consecutive energies
  const float4 e4 = *reinterpret_cast<const float4*>(E + b * TT + tid * 4);
  float m = fmaxf(fmaxf(e4.x, e4.y), fmaxf(e4.z, e4.w));
  red[tid] = m;
  __syncthreads();
  for (int off = 128; off > 0; off >>= 1) {
    if (tid < off) red[tid] = fmaxf(red[tid], red[tid + off]);
    __syncthreads();
  }
  const float mx = red[0];
  __syncthreads();

  const float w0 = __expf(e4.x - mx);
  const float w1 = __expf(e4.y - mx);
  const float w2 = __expf(e4.z - mx);
  const float w3 = __expf(e4.w - mx);
  we[tid * 4 + 0] = w0;
  we[tid * 4 + 1] = w1;
  we[tid * 4 + 2] = w2;
  we[tid * 4 + 3] = w3;
  red[tid] = w0 + w1 + w2 + w3;
  __syncthreads();
  for (int off = 128; off > 0; off >>= 1) {
    if (tid < off) red[tid] += red[tid + off];
    __syncthreads();
  }
  const float rs = 1.f / red[0];

  // context chunk: t in [tc*64, tc*64+64)
  const float* xb = x + (size_t)(b * TT + tc * 64) * DD;
  float ax = 0.f, ay = 0.f;
#pragma unroll 4
  for (int i = 0; i < 64; ++i) {
    const float w = we[tc * 64 + i];
    const float2 xv = *reinterpret_cast<const float2*>(xb + i * DD + tid * 2);
    ax = fmaf(w, xv.x, ax);
    ay = fmaf(w, xv.y, ay);
  }
  atomicAdd(out + b * DD + tid * 2 + 0, ax * rs);
  atomicAdd(out + b * DD + tid * 2 + 1, ay * rs);
}

// ---------------------------------------------------------------------------
extern "C" void kernel_launch(void* const* d_in, const int* in_sizes, int n_in,
                              void* d_out, int out_size, void* d_ws,
                              size_t ws_size, hipStream_t stream) {
  const float* cbhg = (const float*)d_in[0];  // [B, T, D]
  const float* rnn = (const float*)d_in[1];   // [B, D]
  const float* W1 = (const float*)d_in[2];    // [2D, H]
  const float* b1 = (const float*)d_in[3];    // [H]
  const float* W2 = (const float*)d_in[4];    // [H, 1]
  const float* b2 = (const float*)d_in[5];    // [1]
  float* out = (float*)d_out;                 // context [B,D] then rnn [B,D]

  float* E = (float*)d_ws;      // [B*T]
  float* cbh = E + BB * TT;     // [B*H]

  k0_init<<<BB, 256, 0, stream>>>(rnn, W1, b1, out, cbh);
  kA_energies<<<1024, 256, 0, stream>>>(cbhg, W1, cbh, W2, b2, E);
  kB_context<<<BB * 16, 256, 0, stream>>>(cbhg, E, out);
}

// Round 2
// 117.894 us; speedup vs baseline: 1.1134x; 1.1134x over previous
//
#include <hip/hip_runtime.h>

#define BB 32
#define TT 1024
#define DD 512
#define HH 10
#define WP 12            // padded W1a row (10 -> 12 floats, 16B-friendly)
#define CHUNK 64
#define NCH (TT / CHUNK) // 16 chunks per batch row

// ws layout (floats):
//   [0)            Wpad  : DD*WP        = 6144
//   [6144)         cbh   : BB*HH        = 320
//   [6656)         pc    : BB*NCH*DD    = 262144   (16B aligned: 6656*4 % 16 == 0)
//   [268800)       sc    : BB*NCH       = 512

// ---------------------------------------------------------------------------
// k0: copy rnn -> second output half; cbh[b][h] = rnn[b]·W1[D:,h] + b1[h];
//     build padded/aligned Wpad[f][0..11] from W1[:D].
// ---------------------------------------------------------------------------
__global__ __launch_bounds__(256) void k0_init(
    const float* __restrict__ rnn, const float* __restrict__ W1,
    const float* __restrict__ b1, float* __restrict__ out,
    float* __restrict__ cbh, float* __restrict__ wpad) {
  const int b = blockIdx.x;
  const int tid = threadIdx.x;

  const float r0 = rnn[b * DD + tid];
  const float r1 = rnn[b * DD + tid + 256];

  out[BB * DD + b * DD + tid] = r0;
  out[BB * DD + b * DD + tid + 256] = r1;

  // Wpad: block b fills f in [16b, 16b+16)
  if (tid < 16 * WP) {
    const int idx = b * 16 * WP + tid;
    const int f = idx / WP;
    const int h = idx % WP;
    wpad[idx] = (h < HH) ? W1[f * HH + h] : 0.f;
  }

  float s[HH];
#pragma unroll
  for (int h = 0; h < HH; ++h)
    s[h] = r0 * W1[(DD + tid) * HH + h] + r1 * W1[(DD + tid + 256) * HH + h];

  __shared__ float red[256][HH];
#pragma unroll
  for (int h = 0; h < HH; ++h) red[tid][h] = s[h];
  __syncthreads();
  for (int off = 128; off > 0; off >>= 1) {
    if (tid < off) {
#pragma unroll
      for (int h = 0; h < HH; ++h) red[tid][h] += red[tid + off][h];
    }
    __syncthreads();
  }
  if (tid < HH) cbh[b * HH + tid] = red[0][tid] + b1[tid];
}

// ---------------------------------------------------------------------------
// k1: fused energies + softmax numerator + partial context.
//     Block = (b, 64-row chunk), 256 threads = 4 waves.
//     Phase A: wave wv covers f in [128wv,128wv+128), lane = row.
//              Weight addresses are wave-uniform -> scalar loads.
//     Phase B: thread = d-pair, loop rows (chunk is L2-hot from phase A).
// ---------------------------------------------------------------------------
__global__ __launch_bounds__(256, 2) void k1_fused(
    const float* __restrict__ x, const float* __restrict__ wpad,
    const float* __restrict__ cbh, const float* __restrict__ W2,
    const float* __restrict__ b2, float* __restrict__ pc,
    float* __restrict__ sc) {
  const int b = blockIdx.x >> 4;
  const int tc = blockIdx.x & 15;
  const int lane = threadIdx.x & 63;
  const int wv = __builtin_amdgcn_readfirstlane(threadIdx.x >> 6);  // uniform

  __shared__ float hpart[4][CHUNK][13];  // pad 13: conflict-free columns
  __shared__ float wgt[CHUNK];

  // ---- Phase A: energies -------------------------------------------------
  const int row = b * TT + tc * CHUNK + lane;
  const float* xr = x + (size_t)row * DD + wv * 128;
  const float* wp = wpad + wv * 128 * WP;

  float acc[HH];
#pragma unroll
  for (int h = 0; h < HH; ++h) acc[h] = 0.f;

#pragma unroll 4
  for (int k = 0; k < 32; ++k) {
    const float4 xv = *reinterpret_cast<const float4*>(xr + k * 4);
    const float xa[4] = {xv.x, xv.y, xv.z, xv.w};
#pragma unroll
    for (int j = 0; j < 4; ++j) {
      const float4 wa = *reinterpret_cast<const float4*>(wp + (k * 4 + j) * WP);
      const float4 wb = *reinterpret_cast<const float4*>(wp + (k * 4 + j) * WP + 4);
      const float2 wc = *reinterpret_cast<const float2*>(wp + (k * 4 + j) * WP + 8);
      const float xs = xa[j];
      acc[0] = fmaf(xs, wa.x, acc[0]);
      acc[1] = fmaf(xs, wa.y, acc[1]);
      acc[2] = fmaf(xs, wa.z, acc[2]);
      acc[3] = fmaf(xs, wa.w, acc[3]);
      acc[4] = fmaf(xs, wb.x, acc[4]);
      acc[5] = fmaf(xs, wb.y, acc[5]);
      acc[6] = fmaf(xs, wb.z, acc[6]);
      acc[7] = fmaf(xs, wb.w, acc[7]);
      acc[8] = fmaf(xs, wc.x, acc[8]);
      acc[9] = fmaf(xs, wc.y, acc[9]);
    }
  }

#pragma unroll
  for (int h = 0; h < HH; ++h) hpart[wv][lane][h] = acc[h];
  __syncthreads();

  // wave 0: finish the 10-dots, tanh, relu, exp -> softmax numerator
  if (threadIdx.x < 64) {
    float e = b2[0];
#pragma unroll
    for (int h = 0; h < HH; ++h) {
      const float v = hpart[0][lane][h] + hpart[1][lane][h] +
                      hpart[2][lane][h] + hpart[3][lane][h] + cbh[b * HH + h];
      const float z = __expf(2.f * v);
      const float th = 1.f - 2.f / (z + 1.f);  // tanh(v)
      e = fmaf(th, W2[h], e);
    }
    // energies bounded by ||W2||_1 + |b2| (tanh in [-1,1]) -> exp safe, no max-sub
    float w = __expf(fmaxf(e, 0.f));
    wgt[lane] = w;
#pragma unroll
    for (int off = 32; off > 0; off >>= 1) w += __shfl_xor(w, off, 64);
    if (lane == 0) sc[b * NCH + tc] = w;
  }
  __syncthreads();

  // ---- Phase B: partial context (chunk data is L2/L3-hot) ----------------
  const int d0 = threadIdx.x * 2;
  const float* xb = x + (size_t)(b * TT + tc * CHUNK) * DD + d0;
  float ax = 0.f, ay = 0.f;
#pragma unroll 8
  for (int r = 0; r < CHUNK; ++r) {
    const float wr = wgt[r];
    const float2 xv = *reinterpret_cast<const float2*>(xb + (size_t)r * DD);
    ax = fmaf(wr, xv.x, ax);
    ay = fmaf(wr, xv.y, ay);
  }
  *reinterpret_cast<float2*>(pc + (size_t)(b * NCH + tc) * DD + d0) =
      make_float2(ax, ay);
}

// ---------------------------------------------------------------------------
// k2: combine partials: context[b][d] = sum_c pc[b][c][d] / sum_c sc[b][c]
// ---------------------------------------------------------------------------
__global__ __launch_bounds__(256) void k2_combine(
    const float* __restrict__ pc, const float* __restrict__ sc,
    float* __restrict__ out) {
  const int b = blockIdx.x;
  const int d0 = threadIdx.x * 2;

  float ssum = 0.f;
#pragma unroll
  for (int c = 0; c < NCH; ++c) ssum += sc[b * NCH + c];

  float ax = 0.f, ay = 0.f;
#pragma unroll
  for (int c = 0; c < NCH; ++c) {
    const float2 v =
        *reinterpret_cast<const float2*>(pc + (size_t)(b * NCH + c) * DD + d0);
    ax += v.x;
    ay += v.y;
  }
  const float inv = 1.f / ssum;
  *reinterpret_cast<float2*>(out + b * DD + d0) = make_float2(ax * inv, ay * inv);
}

// ---------------------------------------------------------------------------
extern "C" void kernel_launch(void* const* d_in, const int* in_sizes, int n_in,
                              void* d_out, int out_size, void* d_ws,
                              size_t ws_size, hipStream_t stream) {
  const float* cbhg = (const float*)d_in[0];  // [B, T, D]
  const float* rnn = (const float*)d_in[1];   // [B, D]
  const float* W1 = (const float*)d_in[2];    // [2D, H]
  const float* b1 = (const float*)d_in[3];    // [H]
  const float* W2 = (const float*)d_in[4];    // [H, 1]
  const float* b2 = (const float*)d_in[5];    // [1]
  float* out = (float*)d_out;                 // context [B,D] then rnn [B,D]

  float* wpad = (float*)d_ws;                 // 6144
  float* cbh = wpad + DD * WP;                // 320
  float* pc = wpad + 6656;                    // 262144
  float* sc = pc + BB * NCH * DD;             // 512

  k0_init<<<BB, 256, 0, stream>>>(rnn, W1, b1, out, cbh, wpad);
  k1_fused<<<BB * NCH, 256, 0, stream>>>(cbhg, wpad, cbh, W2, b2, pc, sc);
  k2_combine<<<BB, 256, 0, stream>>>(pc, sc, out);
}